// Round 7
// baseline (124.724 us; speedup 1.0000x reference)
//
#include <hip/hip_runtime.h>

#define BB 4
#define MM 128
#define LL 512
#define DD 768
#define NEGF (-1e30f)
#define REPS 5
#define HALF ((size_t)BB * MM * DD)

// DIAGNOSTIC ROUND: r5 structure (best known: 256 thr = 4 waves, float4/lane,
// 768 blocks = 3/CU), but the whole computation repeats REPS times inside the
// kernel (asm memory clobber defeats cross-rep CSE; each rep stores partials
// to its own ws region so no rep is dead code). Last rep's partials are merged
// into d_out by kernel2 -> output identical to r5. Purpose: slope/intercept
// split of the unexplained ~14 us fixed cost (cold caches / I$ / ramp vs
// steady-state stalls) + finally get kernel1 into the top-5 counter rows.
__global__ __launch_bounds__(256, 3) void mention_max_part(
    const float* __restrict__ h, const int* __restrict__ mask,
    float* __restrict__ ws)
{
    const int lane = threadIdx.x & 63;
    const int wave = threadIdx.x >> 6;     // 0..3
    const int dch  = blockIdx.x;           // 0..2
    const int mch  = blockIdx.y >> 2;      // 0..15
    const int lh   = blockIdx.y & 3;       // 0..3
    const int b    = blockIdx.z;           // 0..3

    const int d0 = dch * 256 + lane * 4;
    const int m0 = mch * 8;
    const int l0 = lh * 128 + wave * 32;   // wave owns [l0, l0+32)

    // lane->l mask pointer, clamped in-bounds (bits >=32 unused).
    const int lclamp = (l0 + lane < LL) ? (l0 + lane) : (LL - 1);
    const int* mp = mask + ((size_t)(b * MM + m0)) * LL + lclamp;

    __shared__ float4 red[4][8][64];       // 32 KB

#pragma unroll 1
    for (int rep = 0; rep < REPS; ++rep) {
        asm volatile("" ::: "memory");     // force full reload/recompute per rep

        unsigned bits[8];
#pragma unroll
        for (int m = 0; m < 8; ++m) {
            unsigned long long bl = __ballot(mp[m * LL] != 0);
            bits[m] = (unsigned)__builtin_amdgcn_readfirstlane((int)(unsigned)bl);
        }

        float4 acc[8];
#pragma unroll
        for (int m = 0; m < 8; ++m) acc[m] = make_float4(NEGF, NEGF, NEGF, NEGF);

#pragma unroll
        for (int s = 0; s < 2; ++s) {
            const float4* hp =
                (const float4*)(h + ((size_t)(b * LL + l0 + s * 16)) * DD + d0);
            float4 hreg[16];
#pragma unroll
            for (int i = 0; i < 16; ++i) hreg[i] = hp[(size_t)i * (DD / 4)];

#pragma unroll
            for (int m = 0; m < 8; ++m) {
                const unsigned w = bits[m];
                float4 a = acc[m];
#pragma unroll
                for (int i = 0; i < 16; i += 2) {
                    const int k = s * 16 + i;
                    const float ad0 = ((w >> k) & 1u) ? 0.0f : NEGF;
                    const float ad1 = ((w >> (k + 1)) & 1u) ? 0.0f : NEGF;
                    a.x = fmaxf(fmaxf(hreg[i].x + ad0, hreg[i + 1].x + ad1), a.x);
                    a.y = fmaxf(fmaxf(hreg[i].y + ad0, hreg[i + 1].y + ad1), a.y);
                    a.z = fmaxf(fmaxf(hreg[i].z + ad0, hreg[i + 1].z + ad1), a.z);
                    a.w = fmaxf(fmaxf(hreg[i].w + ad0, hreg[i + 1].w + ad1), a.w);
                }
                acc[m] = a;
            }
        }

#pragma unroll
        for (int m = 0; m < 8; ++m) red[wave][m][lane] = acc[m];
        __syncthreads();

#pragma unroll
        for (int r = 0; r < 2; ++r) {
            const int o  = (int)threadIdx.x + r * 256;  // 0..511
            const int m  = o >> 6;
            const int dp = o & 63;
            float4 v = red[0][m][dp];
#pragma unroll
            for (int w = 1; w < 4; ++w) {
                const float4 u = red[w][m][dp];
                v.x = fmaxf(v.x, u.x);
                v.y = fmaxf(v.y, u.y);
                v.z = fmaxf(v.z, u.z);
                v.w = fmaxf(v.w, u.w);
            }
            // ws region layout: [rep][lh][b][m][d]
            ((float4*)(ws + ((size_t)(rep * 4 + lh)) * HALF +
                       ((size_t)(b * MM + m0 + m)) * DD + dch * 256))[dp] = v;
        }
        __syncthreads();                   // WAR: red reused next rep
    }
}

// Merge the LAST rep's 4 lh partials -> out.
__global__ __launch_bounds__(256) void mention_max_merge(
    const float* __restrict__ ws, float* __restrict__ out)
{
    const int i = (int)(blockIdx.x * blockDim.x + threadIdx.x);  // float4 idx
    const float* base = ws + (size_t)(REPS - 1) * 4 * HALF;
    float4 v = ((const float4*)base)[i];
#pragma unroll
    for (int p = 1; p < 4; ++p) {
        const float4 u = ((const float4*)(base + p * HALF))[i];
        v.x = fmaxf(v.x, u.x);
        v.y = fmaxf(v.y, u.y);
        v.z = fmaxf(v.z, u.z);
        v.w = fmaxf(v.w, u.w);
    }
    ((float4*)out)[i] = v;
}

extern "C" void kernel_launch(void* const* d_in, const int* in_sizes, int n_in,
                              void* d_out, int out_size, void* d_ws, size_t ws_size,
                              hipStream_t stream) {
    const float* h    = (const float*)d_in[0];
    const int*   mask = (const int*)d_in[1];
    float*       out  = (float*)d_out;
    float*       ws   = (float*)d_ws;
    dim3 grid1(DD / 256, (MM / 8) * 4, BB);
    mention_max_part<<<grid1, dim3(256), 0, stream>>>(h, mask, ws);
    const int n4 = BB * MM * DD / 4;       // 98304 float4
    mention_max_merge<<<n4 / 256, dim3(256), 0, stream>>>(ws, out);
}

// Round 8
// 73.091 us; speedup vs baseline: 1.7064x; 1.7064x over previous
//
#include <hip/hip_runtime.h>

#define BB 4
#define MM 128
#define LL 512
#define DD 768
#define NEGF (-1e30f)
#define HALF  ((size_t)BB * MM * DD)      // floats per lh partial
#define HALF4 (HALF / 4)                  // float4s per lh partial

// Monotone float<->uint encode for unsigned-max reduction (bijective).
__device__ __forceinline__ unsigned enc(float x) {
    int b = __float_as_int(x);
    return (unsigned)(b ^ ((b >> 31) | 0x80000000));
}
__device__ __forceinline__ float dec(unsigned u) {
    int b = (u & 0x80000000u) ? (int)(u ^ 0x80000000u) : ~(int)u;
    return __int_as_float(b);
}

// Kernel1: 256 thr = 4 waves. Grid (3 dch, 16 mch x 8 lh, 4 b) = 1536 blocks
// = 6 blocks/CU, 24 waves/CU (launch_bounds(256,6) caps VGPR at ~85; hreg is
// 8 rows x float4 = 32 VGPR + acc 32 to stay under it honestly).
// Wave owns 16 l; one ballot covers 4 m x 16 l (lane = (m&3)*16 + l-off).
// Selects are FORCED scalar: s_bitcmp1_b32 + s_cselect_b32 -> SGPR addend,
// consumed by v_add(v,v,s); core = add-pair + max3 = 1.5 VALU/elem.
// Cross-wave reduce: encoded atomicMax on 8 KB LDS (ds_max_u32, comp-split,
// conflict-free). Partials per lh go to d_ws; kernel2 merges 8 -> out.
__global__ __launch_bounds__(256, 6) void mention_max_part(
    const float* __restrict__ h, const int* __restrict__ mask,
    float* __restrict__ ws)
{
    const int lane = threadIdx.x & 63;
    const int wave = threadIdx.x >> 6;     // 0..3
    const int dch  = blockIdx.x;           // 0..2
    const int mch  = blockIdx.y >> 3;      // 0..15
    const int lh   = blockIdx.y & 7;       // 0..7
    const int b    = blockIdx.z;           // 0..3

    const int m0 = mch * 8;
    const int l0 = lh * 64 + wave * 16;    // wave owns [l0, l0+16)
    const int q  = lane >> 4;              // 0..3 -> m sub-row
    const int lb = lane & 15;              // l offset

    __shared__ unsigned red[8][4][64];     // 8 KB, comp-split
    for (int t = (int)threadIdx.x; t < 8 * 4 * 64; t += 256)
        ((unsigned*)red)[t] = 0u;          // 0 < enc(-1e30): safe floor

    // Two ballots cover all 8 m x 16 l.
    const unsigned long long bal0 =
        __ballot(mask[(size_t)(b * MM + m0 + q) * LL + l0 + lb] != 0);
    const unsigned long long bal1 =
        __ballot(mask[(size_t)(b * MM + m0 + 4 + q) * LL + l0 + lb] != 0);
    unsigned w16[8];
#pragma unroll
    for (int m = 0; m < 4; ++m) {
        w16[m]     = (unsigned)(bal0 >> (m * 16)) & 0xFFFFu;
        w16[m + 4] = (unsigned)(bal1 >> (m * 16)) & 0xFFFFu;
    }

    const unsigned negb = __float_as_uint(NEGF);

    float4 acc[8];
#pragma unroll
    for (int m = 0; m < 8; ++m) acc[m] = make_float4(NEGF, NEGF, NEGF, NEGF);

    // float4-granular h pointer: row stride DD/4 = 192.
    const float4* hp = (const float4*)h +
                       (size_t)(b * LL + l0) * (DD / 4) + dch * 64 + lane;

#pragma unroll
    for (int s = 0; s < 2; ++s) {
        float4 hreg[8];
#pragma unroll
        for (int i = 0; i < 8; ++i) hreg[i] = hp[(size_t)(s * 8 + i) * (DD / 4)];

#pragma unroll
        for (int m = 0; m < 8; ++m) {
            const unsigned w = w16[m];
            float4 a = acc[m];
#pragma unroll
            for (int i = 0; i < 8; i += 2) {
                unsigned adu0, adu1;
                asm("s_bitcmp1_b32 %1, %2\n\t"
                    "s_cselect_b32 %0, 0, %3"
                    : "=s"(adu0) : "s"(w), "i"(s * 8 + i), "s"(negb) : "scc");
                asm("s_bitcmp1_b32 %1, %2\n\t"
                    "s_cselect_b32 %0, 0, %3"
                    : "=s"(adu1) : "s"(w), "i"(s * 8 + i + 1), "s"(negb) : "scc");
                const float ad0 = __uint_as_float(adu0);
                const float ad1 = __uint_as_float(adu1);
                a.x = fmaxf(fmaxf(hreg[i].x + ad0, hreg[i + 1].x + ad1), a.x);
                a.y = fmaxf(fmaxf(hreg[i].y + ad0, hreg[i + 1].y + ad1), a.y);
                a.z = fmaxf(fmaxf(hreg[i].z + ad0, hreg[i + 1].z + ad1), a.z);
                a.w = fmaxf(fmaxf(hreg[i].w + ad0, hreg[i + 1].w + ad1), a.w);
            }
            acc[m] = a;
        }
    }

    __syncthreads();                       // red init visible
#pragma unroll
    for (int m = 0; m < 8; ++m) {
        atomicMax(&red[m][0][lane], enc(acc[m].x));
        atomicMax(&red[m][1][lane], enc(acc[m].y));
        atomicMax(&red[m][2][lane], enc(acc[m].z));
        atomicMax(&red[m][3][lane], enc(acc[m].w));
    }
    __syncthreads();

    // Block output: 8 m x 256 d = 512 float4; 2 per thread -> ws[lh][...]
#pragma unroll
    for (int r = 0; r < 2; ++r) {
        const int o  = (int)threadIdx.x + r * 256;  // 0..511
        const int m  = o >> 6;
        const int dp = o & 63;
        float4 v;
        v.x = dec(red[m][0][dp]);
        v.y = dec(red[m][1][dp]);
        v.z = dec(red[m][2][dp]);
        v.w = dec(red[m][3][dp]);
        ((float4*)ws)[(size_t)lh * HALF4 +
                      (size_t)(b * MM + m0 + m) * (DD / 4) + dch * 64 + dp] = v;
    }
}

// Kernel2: out = elementwise max of the 8 lh partials.
__global__ __launch_bounds__(256) void mention_max_merge(
    const float* __restrict__ ws, float* __restrict__ out)
{
    const int i = (int)(blockIdx.x * blockDim.x + threadIdx.x);  // float4 idx
    float4 v = ((const float4*)ws)[i];
#pragma unroll
    for (int p = 1; p < 8; ++p) {
        const float4 u = ((const float4*)ws)[(size_t)p * HALF4 + i];
        v.x = fmaxf(v.x, u.x);
        v.y = fmaxf(v.y, u.y);
        v.z = fmaxf(v.z, u.z);
        v.w = fmaxf(v.w, u.w);
    }
    ((float4*)out)[i] = v;
}

extern "C" void kernel_launch(void* const* d_in, const int* in_sizes, int n_in,
                              void* d_out, int out_size, void* d_ws, size_t ws_size,
                              hipStream_t stream) {
    const float* h    = (const float*)d_in[0];
    const int*   mask = (const int*)d_in[1];
    float*       out  = (float*)d_out;
    float*       ws   = (float*)d_ws;
    dim3 grid1(DD / 256, (MM / 8) * 8, BB);
    mention_max_part<<<grid1, dim3(256), 0, stream>>>(h, mask, ws);
    const int n4 = BB * MM * DD / 4;       // 98304 float4
    mention_max_merge<<<n4 / 256, dim3(256), 0, stream>>>(ws, out);
}